// Round 7
// baseline (498.798 us; speedup 1.0000x reference)
//
#include <hip/hip_runtime.h>

#define N_NODES 100000
#define NEDGE   3200000
#define DIN     16
#define DIM     128
#define DOUT    16
#define LN_EPS  1e-5f
#define NBINS   391          // 256-target bins: bin = c >> 8
#define CHUNK   4096         // edges per chunk block (smaller -> more parallel CSR build)
#define NPB     782          // ceil(NEDGE / CHUNK)
#define XS_STRIDE 136        // LDS bf16 row stride: 272B, 16B-aligned, 2-way-bank free
#define GGRID   1024         // GEMM grid
#define FP8_SCALE  64.0f     // pack scale: keeps hs out of e4m3 denormal zone
#define FP8_ISCALE 0.015625f

typedef __attribute__((ext_vector_type(8))) __bf16 bfrag_t;
typedef __attribute__((ext_vector_type(4))) float facc_t;
typedef __attribute__((ext_vector_type(2))) float fx2;

static __device__ __forceinline__ facc_t mfma16(bfrag_t a, bfrag_t b, facc_t c) {
    return __builtin_amdgcn_mfma_f32_16x16x32_bf16(a, b, c, 0, 0, 0);
}

// ---- bf16 helpers (RNE pack, cheap unpack) ----
static __device__ __forceinline__ unsigned f2bf(float f) {
    unsigned u = __float_as_uint(f);
    return (u + 0x7fffu + ((u >> 16) & 1u)) >> 16;
}
static __device__ __forceinline__ float bf_lo(unsigned u) { return __uint_as_float(u << 16); }
static __device__ __forceinline__ float bf_hi(unsigned u) { return __uint_as_float(u & 0xFFFF0000u); }

// ---- fp8 e4m3 (OCP on gfx950) HW converts ----
static __device__ __forceinline__ unsigned char f2fp8(float v) {
    return (unsigned char)__builtin_amdgcn_cvt_pk_fp8_f32(v, v, 0u, false);
}

// ---------------- CSR build: deterministic two-table partition ----------------
// pass 1: per-chunk histogram -> chunkhist[c][b]

__global__ __launch_bounds__(256) void k_hist2(const int* __restrict__ col,
                                               int* __restrict__ chunkhist) {
    __shared__ int lh[NBINS];
    int tid = threadIdx.x;
    for (int b = tid; b < NBINS; b += 256) lh[b] = 0;
    __syncthreads();
    int e0 = blockIdx.x * CHUNK;
    int e1 = e0 + CHUNK; if (e1 > NEDGE) e1 = NEDGE;
    for (int e = e0 + tid; e < e1; e += 256)
        atomicAdd(&lh[col[e] >> 8], 1);
    __syncthreads();
    int* out = chunkhist + (size_t)blockIdx.x * NBINS;
    for (int b = tid; b < NBINS; b += 256) out[b] = lh[b];
}

// pass 2a: bin totals (one block per bin, parallel over chunks)
__global__ __launch_bounds__(256) void k_scanA(const int* __restrict__ chunkhist,
                                               int* __restrict__ bintot) {
    __shared__ int sh[256];
    int b = blockIdx.x, t = threadIdx.x;
    int s = 0;
    for (int c = t; c < NPB; c += 256) s += chunkhist[(size_t)c * NBINS + b];
    sh[t] = s;
    __syncthreads();
    for (int off = 128; off > 0; off >>= 1) {
        if (t < off) sh[t] += sh[t + off];
        __syncthreads();
    }
    if (t == 0) bintot[b] = sh[0];
}

// pass 2b: per-bin prefix over chunks (one block per bin); each block derives
// its own binbase[b] = prefix of bintot (no serial scan kernel needed)
__global__ __launch_bounds__(256) void k_scanC(const int* __restrict__ chunkhist,
                                               const int* __restrict__ bintot,
                                               int* __restrict__ binbase,
                                               int* __restrict__ chunkbase) {
    __shared__ int sh[256];
    __shared__ int carry_s;
    int b = blockIdx.x, t = threadIdx.x;
    {   // base = sum of bintot[0..b-1]
        int s = 0;
        for (int i = t; i < b; i += 256) s += bintot[i];
        sh[t] = s;
        __syncthreads();
        for (int off = 128; off > 0; off >>= 1) {
            if (t < off) sh[t] += sh[t + off];
            __syncthreads();
        }
        if (t == 0) {
            carry_s = sh[0];
            binbase[b] = sh[0];
            if (b == 0) binbase[NBINS] = NEDGE;
        }
        __syncthreads();
    }
    const int ROUNDS = (NPB + 255) / 256;
    for (int r = 0; r < ROUNDS; r++) {
        int idx = r * 256 + t;
        int v = (idx < NPB) ? chunkhist[(size_t)idx * NBINS + b] : 0;
        sh[t] = v;
        __syncthreads();
        for (int off = 1; off < 256; off <<= 1) {
            int a = (t >= off) ? sh[t - off] : 0;
            __syncthreads();
            sh[t] += a;
            __syncthreads();
        }
        int incl = sh[t];
        int carry = carry_s;
        if (idx < NPB) chunkbase[(size_t)idx * NBINS + b] = carry + incl - v;
        __syncthreads();
        if (t == 255) carry_s = carry + incl;
        __syncthreads();
    }
}

// pass 3: single sweep over edges; scatter packed pairs at precomputed bases
__global__ __launch_bounds__(256) void k_binpass2(const int* __restrict__ row, const int* __restrict__ col,
                                                  const int* __restrict__ chunkbase,
                                                  unsigned* __restrict__ pairs) {
    __shared__ int lbase[NBINS], lofs[NBINS];
    int tid = threadIdx.x;
    const int* cb = chunkbase + (size_t)blockIdx.x * NBINS;
    for (int b = tid; b < NBINS; b += 256) { lbase[b] = cb[b]; lofs[b] = 0; }
    __syncthreads();
    int e0 = blockIdx.x * CHUNK;
    int e1 = e0 + CHUNK; if (e1 > NEDGE) e1 = NEDGE;
    for (int e = e0 + tid; e < e1; e += 256) {
        int c = col[e];
        int b = c >> 8;
        int pos = atomicAdd(&lofs[b], 1);
        pairs[lbase[b] + pos] = ((unsigned)(c & 255) << 17) | (unsigned)row[e];
    }
}

// pass 4: one block per bin -> per-node counts, indptr, dinv, scatter rows_s
__global__ __launch_bounds__(256) void k_csr2(const unsigned* __restrict__ pairs,
                                              const int* __restrict__ binbase,
                                              int* __restrict__ indptr, float* __restrict__ dinv,
                                              int* __restrict__ rows_s) {
    __shared__ int lcnt[256], lptr[256], lofs[256];
    __shared__ int wsum[4];
    int tid = threadIdx.x;
    int b = blockIdx.x;
    int n0 = b << 8;
    int base = binbase[b], end = binbase[b + 1];
    lcnt[tid] = 0; lofs[tid] = 0;
    __syncthreads();
    for (int s = base + tid; s < end; s += 256)
        atomicAdd(&lcnt[pairs[s] >> 17], 1);
    __syncthreads();
    int v = lcnt[tid];
    int lane = tid & 63, w = tid >> 6;
    int s = v;
    for (int off = 1; off < 64; off <<= 1) {
        int t = __shfl_up(s, off);
        if (lane >= off) s += t;
    }
    if (lane == 63) wsum[w] = s;
    __syncthreads();
    int add = 0;
    for (int k = 0; k < w; k++) add += wsum[k];
    int excl = add + s - v;
    lptr[tid] = excl;
    int node = n0 + tid;
    if (node < N_NODES) {
        indptr[node] = base + excl;
        dinv[node] = rsqrtf((float)(v + 1));   // +1 self loop
    }
    if (b == NBINS - 1 && tid == 0) indptr[N_NODES] = NEDGE;
    __syncthreads();
    for (int s2 = base + tid; s2 < end; s2 += 256) {
        unsigned p = pairs[s2];
        int cl = p >> 17;
        int r  = p & 0x1FFFF;
        int dst = base + lptr[cl] + atomicAdd(&lofs[cl], 1);
        rows_s[dst] = r;
    }
}

// ---------------- MFMA helpers ----------------
template<int NC, int NT>
static __device__ __forceinline__ void load_bfrags(const float* __restrict__ W, int colbase,
                                                   int lane, bfrag_t B[NT][4]) {
    int q = lane >> 4, nn = lane & 15;
    #pragma unroll
    for (int nt = 0; nt < NT; nt++) {
        int col = colbase + 16 * nt + nn;
        #pragma unroll
        for (int kc = 0; kc < 4; kc++) {
            int k0 = 32 * kc + 8 * q;
            bfrag_t f;
            #pragma unroll
            for (int j = 0; j < 8; j++)
                f[j] = (__bf16)W[(size_t)(k0 + j) * NC + col];
            B[nt][kc] = f;
        }
    }
}

// ---------------- encoder (fused): x_bf16 = relu(X@W0+b0)@W1+b1 ; hs = fp8((x@Wc)*dinv*64) ----------------

__global__ __launch_bounds__(256) void k_encC(const float* __restrict__ X,
                                              const float* __restrict__ W0, const float* __restrict__ b0,
                                              const float* __restrict__ W1, const float* __restrict__ b1,
                                              const float* __restrict__ Wc, const float* __restrict__ dinv,
                                              unsigned short* __restrict__ xo, unsigned char* __restrict__ hs_out) {
    __shared__ short xs[32 * XS_STRIDE];
    __shared__ float W0s[DIN * DIM];   // 8 KB
    __shared__ float b0s[DIM];
    int tid = threadIdx.x, lane = tid & 63, wv = tid >> 6;
    for (int i = tid; i < DIN * DIM / 4; i += 256) ((float4*)W0s)[i] = ((const float4*)W0)[i];
    if (tid < DIM) b0s[tid] = b0[tid];
    bfrag_t B[2][4];
    load_bfrags<DIM, 2>(W1, 32 * wv, lane, B);
    bfrag_t Bc[2][4];
    load_bfrags<DIM, 2>(Wc, 32 * wv, lane, Bc);
    int q = lane >> 4, nn = lane & 15;
    float bias[2] = { b1[32 * wv + nn], b1[32 * wv + 16 + nn] };
    const int ngroups = N_NODES / 32;
    for (int g = blockIdx.x; g < ngroups; g += gridDim.x) {
        int n0 = g * 32;
        __syncthreads();
        {   // stage: t = relu(X@W0+b0), node r, cols 16s..16s+15 -> bf16 LDS
            int r = tid >> 3, s = tid & 7;
            float xr[DIN];
            const float4* xsrc = (const float4*)(X + (size_t)(n0 + r) * DIN);
            #pragma unroll
            for (int i = 0; i < 4; i++) {
                float4 v = xsrc[i];
                xr[4*i] = v.x; xr[4*i+1] = v.y; xr[4*i+2] = v.z; xr[4*i+3] = v.w;
            }
            unsigned pk[8];
            #pragma unroll
            for (int cc = 0; cc < 16; cc += 2) {
                int c0 = 16 * s + cc;
                float a0 = b0s[c0], a1 = b0s[c0 + 1];
                #pragma unroll
                for (int k = 0; k < DIN; k++) {
                    float2 w = *(const float2*)&W0s[k * DIM + c0];
                    a0 += xr[k] * w.x; a1 += xr[k] * w.y;
                }
                pk[cc >> 1] = f2bf(fmaxf(a0, 0.f)) | (f2bf(fmaxf(a1, 0.f)) << 16);
            }
            *(uint4*)&xs[r * XS_STRIDE + 16 * s] = *(uint4*)&pk[0];
            *(uint4*)&xs[r * XS_STRIDE + 16 * s + 8] = *(uint4*)&pk[4];
        }
        __syncthreads();
        facc_t acc[2][2];
        #pragma unroll
        for (int mt = 0; mt < 2; mt++)
            #pragma unroll
            for (int nt = 0; nt < 2; nt++)
                acc[mt][nt] = (facc_t){bias[nt], bias[nt], bias[nt], bias[nt]};
        #pragma unroll
        for (int kc = 0; kc < 4; kc++) {
            bfrag_t a0 = *(const bfrag_t*)&xs[nn * XS_STRIDE + 32 * kc + 8 * q];
            bfrag_t a1 = *(const bfrag_t*)&xs[(16 + nn) * XS_STRIDE + 32 * kc + 8 * q];
            acc[0][0] = mfma16(a0, B[0][kc], acc[0][0]);
            acc[0][1] = mfma16(a0, B[1][kc], acc[0][1]);
            acc[1][0] = mfma16(a1, B[0][kc], acc[1][0]);
            acc[1][1] = mfma16(a1, B[1][kc], acc[1][1]);
        }
        // write x (bf16) and re-stage x tile as bf16 for the fused conv
        __syncthreads();   // all A-reads done; xs can be overwritten
        #pragma unroll
        for (int mt = 0; mt < 2; mt++)
            #pragma unroll
            for (int r = 0; r < 4; r++) {
                int node = n0 + 16 * mt + 4 * q + r;
                int nl = 16 * mt + 4 * q + r;
                #pragma unroll
                for (int nt = 0; nt < 2; nt++) {
                    int col = 32 * wv + 16 * nt + nn;
                    unsigned short bv = (unsigned short)f2bf(acc[mt][nt][r]);
                    xo[(size_t)node * DIM + col] = bv;
                    xs[nl * XS_STRIDE + col] = (short)bv;
                }
            }
        __syncthreads();
        {   // conv tail from LDS tile
            facc_t a2[2][2] = {};
            #pragma unroll
            for (int kc = 0; kc < 4; kc++) {
                bfrag_t a0 = *(const bfrag_t*)&xs[nn * XS_STRIDE + 32 * kc + 8 * q];
                bfrag_t a1 = *(const bfrag_t*)&xs[(16 + nn) * XS_STRIDE + 32 * kc + 8 * q];
                a2[0][0] = mfma16(a0, Bc[0][kc], a2[0][0]);
                a2[0][1] = mfma16(a0, Bc[1][kc], a2[0][1]);
                a2[1][0] = mfma16(a1, Bc[0][kc], a2[1][0]);
                a2[1][1] = mfma16(a1, Bc[1][kc], a2[1][1]);
            }
            #pragma unroll
            for (int mt = 0; mt < 2; mt++)
                #pragma unroll
                for (int r = 0; r < 4; r++) {
                    int node = n0 + 16 * mt + 4 * q + r;
                    float d64 = dinv[node] * FP8_SCALE;
                    #pragma unroll
                    for (int nt = 0; nt < 2; nt++)
                        hs_out[(size_t)node * DIM + 32 * wv + 16 * nt + nn] =
                            f2fp8(a2[mt][nt][r] * d64);
                }
        }
    }
}

// ---------------- conv: hs_fp8 = fp8((x_bf16 @ W_conv) * dinv * 64) ----------------
// LDS-free: A-fragments are 16B-aligned contiguous row slices -> load direct from
// global (L2-hot). No stage, no barriers — pure load+MFMA+store, occupancy hides latency.

__global__ __launch_bounds__(256) void k_convM(const unsigned short* __restrict__ xi,
                                               const float* __restrict__ W,
                                               const float* __restrict__ dinv,
                                               unsigned char* __restrict__ hs) {
    int tid = threadIdx.x, lane = tid & 63, wv = tid >> 6;
    bfrag_t B[2][4];
    load_bfrags<DIM, 2>(W, 32 * wv, lane, B);
    int q = lane >> 4, nn = lane & 15;
    const int ngroups = N_NODES / 32;
    for (int g = blockIdx.x; g < ngroups; g += gridDim.x) {
        int n0 = g * 32;
        const unsigned short* r0p = xi + (size_t)(n0 + nn) * DIM + 8 * q;
        const unsigned short* r1p = xi + (size_t)(n0 + 16 + nn) * DIM + 8 * q;
        facc_t a2[2][2] = {};
        #pragma unroll
        for (int kc = 0; kc < 4; kc++) {
            bfrag_t a0 = *(const bfrag_t*)(r0p + 32 * kc);
            bfrag_t a1 = *(const bfrag_t*)(r1p + 32 * kc);
            a2[0][0] = mfma16(a0, B[0][kc], a2[0][0]);
            a2[0][1] = mfma16(a0, B[1][kc], a2[0][1]);
            a2[1][0] = mfma16(a1, B[0][kc], a2[1][0]);
            a2[1][1] = mfma16(a1, B[1][kc], a2[1][1]);
        }
        #pragma unroll
        for (int mt = 0; mt < 2; mt++)
            #pragma unroll
            for (int r = 0; r < 4; r++) {
                int node = n0 + 16 * mt + 4 * q + r;
                float d64 = dinv[node] * FP8_SCALE;
                #pragma unroll
                for (int nt = 0; nt < 2; nt++)
                    hs[(size_t)node * DIM + 32 * wv + 16 * nt + nn] =
                        f2fp8(a2[mt][nt][r] * d64);
            }
    }
}

// ---------------- fused gather + residual + bias + LayerNorm (hs fp8, x bf16) ----------------
// packed-f32 accumulation: fx2 += fx2 lowers to v_pk_add_f32 (VOP3P)

static __device__ __forceinline__ void accp(fx2* __restrict__ acc, uint2 u) {
    acc[0] += __builtin_amdgcn_cvt_pk_f32_fp8(u.x, false);
    acc[1] += __builtin_amdgcn_cvt_pk_f32_fp8(u.x, true);
    acc[2] += __builtin_amdgcn_cvt_pk_f32_fp8(u.y, false);
    acc[3] += __builtin_amdgcn_cvt_pk_f32_fp8(u.y, true);
}

__global__ __launch_bounds__(256) void k_agg_ln(const uint2* __restrict__ hs2, uint4* __restrict__ x4,
                                                const float* __restrict__ dinv,
                                                const int* __restrict__ indptr,
                                                const int* __restrict__ rows_s,
                                                const float* __restrict__ bconv,
                                                const float* __restrict__ g_, const float* __restrict__ b_) {
    int v = (blockIdx.x * blockDim.x + threadIdx.x) >> 6;
    int lane = threadIdx.x & 63;
    if (v >= N_NODES) return;
    int sub = lane >> 4, part = lane & 15;
    fx2 acc[4];
    #pragma unroll
    for (int j = 0; j < 4; j++) acc[j] = (fx2){0.f, 0.f};
    {   // self loop: count once (sub 0 only)
        uint2 u = hs2[(size_t)v * 16 + part];
        if (sub == 0) accp(acc, u);
    }
    int beg = indptr[v], end = indptr[v + 1];
    for (int base = beg; base < end; base += 64) {
        int m = end - base; if (m > 64) m = 64;
        int r0 = rows_s[base + (lane < m ? lane : m - 1)];
        // hoist ALL index shuffles off the load critical path (depend only on r0)
        int idx[16];
        #pragma unroll
        for (int j = 0; j < 16; j++) idx[j] = __shfl(r0, 4 * j + sub);
        int full = m >> 2;            // 4-edge groups with all lanes valid
        int j = 0;
        for (; j + 4 <= full; j += 4) {   // 4 independent loads in flight
            uint2 ua = hs2[(size_t)idx[j]     * 16 + part];
            uint2 ub = hs2[(size_t)idx[j + 1] * 16 + part];
            uint2 uc = hs2[(size_t)idx[j + 2] * 16 + part];
            uint2 ud = hs2[(size_t)idx[j + 3] * 16 + part];
            accp(acc, ua); accp(acc, ub); accp(acc, uc); accp(acc, ud);
        }
        for (; j < full; j++) {
            uint2 u = hs2[(size_t)idx[j] * 16 + part];
            accp(acc, u);
        }
        if (4 * full < m) {           // partial group: lanes with 4*full+sub < m
            bool valid = (4 * full + sub) < m;
            uint2 u = hs2[(size_t)idx[full] * 16 + part];   // clamped index, safe
            if (valid) accp(acc, u);
        }
    }
    float a8[8];
    #pragma unroll
    for (int j = 0; j < 4; j++) { a8[2 * j] = acc[j][0]; a8[2 * j + 1] = acc[j][1]; }
    #pragma unroll
    for (int j = 0; j < 8; j++) {             // sum the 4 sub-copies
        a8[j] += __shfl_xor(a8[j], 16);
        a8[j] += __shfl_xor(a8[j], 32);
    }
    float dvs = dinv[v] * FP8_ISCALE;         // undo FP8_SCALE here
    float y[8];
    {
        uint4 xu = x4[(size_t)v * 16 + part];
        const float4* bc = (const float4*)(bconv + 8 * part);
        float4 b0 = bc[0], b1 = bc[1];
        y[0] = bf_lo(xu.x) + dvs * a8[0] + b0.x; y[1] = bf_hi(xu.x) + dvs * a8[1] + b0.y;
        y[2] = bf_lo(xu.y) + dvs * a8[2] + b0.z; y[3] = bf_hi(xu.y) + dvs * a8[3] + b0.w;
        y[4] = bf_lo(xu.z) + dvs * a8[4] + b1.x; y[5] = bf_hi(xu.z) + dvs * a8[5] + b1.y;
        y[6] = bf_lo(xu.w) + dvs * a8[6] + b1.z; y[7] = bf_hi(xu.w) + dvs * a8[7] + b1.w;
    }
    float s = 0.f, s2 = 0.f;
    #pragma unroll
    for (int j = 0; j < 8; j++) { s += y[j]; s2 += y[j] * y[j]; }
    #pragma unroll
    for (int off = 1; off < 16; off <<= 1) {  // reduce within 16-lane group (covers all parts)
        s += __shfl_xor(s, off);
        s2 += __shfl_xor(s2, off);
    }
    float mu = s * (1.f / 128.f);
    float rstd = rsqrtf(s2 * (1.f / 128.f) - mu * mu + LN_EPS);
    if (sub == 0) {
        const float4* gp = (const float4*)(g_ + 8 * part);
        const float4* bp = (const float4*)(b_ + 8 * part);
        float4 g0 = gp[0], g1 = gp[1];
        float4 bb0 = bp[0], bb1 = bp[1];
        float o[8];
        o[0] = (y[0] - mu) * rstd * g0.x + bb0.x;
        o[1] = (y[1] - mu) * rstd * g0.y + bb0.y;
        o[2] = (y[2] - mu) * rstd * g0.z + bb0.z;
        o[3] = (y[3] - mu) * rstd * g0.w + bb0.w;
        o[4] = (y[4] - mu) * rstd * g1.x + bb1.x;
        o[5] = (y[5] - mu) * rstd * g1.y + bb1.y;
        o[6] = (y[6] - mu) * rstd * g1.z + bb1.z;
        o[7] = (y[7] - mu) * rstd * g1.w + bb1.w;
        uint4 ow;
        ow.x = f2bf(o[0]) | (f2bf(o[1]) << 16);
        ow.y = f2bf(o[2]) | (f2bf(o[3]) << 16);
        ow.z = f2bf(o[4]) | (f2bf(o[5]) << 16);
        ow.w = f2bf(o[6]) | (f2bf(o[7]) << 16);
        x4[(size_t)v * 16 + part] = ow;
    }
}

// ---------------- decoder (fused): out = relu(x@W0+b0)@W1 + b1 ----------------
// phase-1 A-frags direct from global; LDS only for the cross-wave t2 tile.

__global__ __launch_bounds__(256) void k_decM(const unsigned short* __restrict__ xi,
                                              const float* __restrict__ W0, const float* __restrict__ b0f,
                                              const float* __restrict__ W1, const float* __restrict__ b1f,
                                              float* __restrict__ out) {
    __shared__ short xs[32 * XS_STRIDE];
    int tid = threadIdx.x, lane = tid & 63, wv = tid >> 6;
    bfrag_t B0[2][4];
    load_bfrags<DIM, 2>(W0, 32 * wv, lane, B0);
    int q = lane >> 4, nn = lane & 15;
    bfrag_t B1[4];
    #pragma unroll
    for (int kc = 0; kc < 4; kc++) {
        int k0 = 32 * kc + 8 * q;
        bfrag_t f;
        #pragma unroll
        for (int j = 0; j < 8; j++)
            f[j] = (__bf16)W1[(size_t)(k0 + j) * DOUT + nn];
        B1[kc] = f;
    }
    float bias0[2] = { b0f[32 * wv + nn], b0f[32 * wv + 16 + nn] };
    float bias1 = b1f[nn];
    const int ngroups = N_NODES / 32;
    for (int g = blockIdx.x; g < ngroups; g += gridDim.x) {
        int n0 = g * 32;
        __syncthreads();   // prev iteration's phase-2 reads of xs complete
        const unsigned short* r0p = xi + (size_t)(n0 + nn) * DIM + 8 * q;
        const unsigned short* r1p = xi + (size_t)(n0 + 16 + nn) * DIM + 8 * q;
        facc_t acc[2][2];
        #pragma unroll
        for (int mt = 0; mt < 2; mt++)
            #pragma unroll
            for (int nt = 0; nt < 2; nt++)
                acc[mt][nt] = (facc_t){bias0[nt], bias0[nt], bias0[nt], bias0[nt]};
        #pragma unroll
        for (int kc = 0; kc < 4; kc++) {
            bfrag_t a0 = *(const bfrag_t*)(r0p + 32 * kc);
            bfrag_t a1 = *(const bfrag_t*)(r1p + 32 * kc);
            acc[0][0] = mfma16(a0, B0[0][kc], acc[0][0]);
            acc[0][1] = mfma16(a0, B0[1][kc], acc[0][1]);
            acc[1][0] = mfma16(a1, B0[0][kc], acc[1][0]);
            acc[1][1] = mfma16(a1, B0[1][kc], acc[1][1]);
        }
        #pragma unroll
        for (int mt = 0; mt < 2; mt++)
            #pragma unroll
            for (int nt = 0; nt < 2; nt++)
                #pragma unroll
                for (int r = 0; r < 4; r++) {
                    int nl = 16 * mt + 4 * q + r;
                    int col = 32 * wv + 16 * nt + nn;
                    xs[nl * XS_STRIDE + col] = (short)f2bf(fmaxf(acc[mt][nt][r], 0.f));
                }
        __syncthreads();
        if (wv < 2) {   // waves 0,1: t2[32x128] @ W1[128x16]
            facc_t acc2 = (facc_t){bias1, bias1, bias1, bias1};
            #pragma unroll
            for (int kc = 0; kc < 4; kc++) {
                bfrag_t a = *(const bfrag_t*)&xs[(16 * wv + nn) * XS_STRIDE + 32 * kc + 8 * q];
                acc2 = mfma16(a, B1[kc], acc2);
            }
            #pragma unroll
            for (int r = 0; r < 4; r++) {
                int node = n0 + 16 * wv + 4 * q + r;
                out[(size_t)node * DOUT + nn] = acc2[r];
            }
        }
    }
}

// ---------------- launch ----------------

extern "C" void kernel_launch(void* const* d_in, const int* in_sizes, int n_in,
                              void* d_out, int out_size, void* d_ws, size_t ws_size,
                              hipStream_t stream) {
    const float* X      = (const float*)d_in[0];
    const float* W_enc0 = (const float*)d_in[1];
    const float* b_enc0 = (const float*)d_in[2];
    const float* W_enc1 = (const float*)d_in[3];
    const float* b_enc1 = (const float*)d_in[4];
    const float* W_conv = (const float*)d_in[5];
    const float* b_conv = (const float*)d_in[6];
    const float* ln_g   = (const float*)d_in[7];
    const float* ln_b   = (const float*)d_in[8];
    const float* W_dec0 = (const float*)d_in[9];
    const float* b_dec0 = (const float*)d_in[10];
    const float* W_dec1 = (const float*)d_in[11];
    const float* b_dec1 = (const float*)d_in[12];
    const int*   erow   = (const int*)d_in[13];         // edge_index[0] = sources
    const int*   ecol   = erow + NEDGE;                 // edge_index[1] = targets
    float* out = (float*)d_out;

    unsigned short* x         = (unsigned short*)d_ws;                       // N*128 bf16 (25.6 MB)
    unsigned char*  hs        = (unsigned char*)(x + (size_t)N_NODES * DIM); // N*128 fp8 (12.8 MB)
    float*          dinv      = (float*)(hs + (size_t)N_NODES * DIM);        // N f32
    int*            indptr    = (int*)(dinv + N_NODES);                      // N+1 int
    int*            binbase   = indptr + N_NODES + 8;                        // NBINS+1
    int*            bintot    = binbase + NBINS + 9;                         // NBINS
    int*            chunkhist = bintot + NBINS + 8;                          // NPB*NBINS
    int*            chunkbase = chunkhist + NPB * NBINS + 8;                 // NPB*NBINS
    int*            rows_s    = chunkbase + NPB * NBINS + 8;                 // E int
    unsigned*       pairs     = (unsigned*)hs;   // overlay: E*4B == N*128B exactly; consumed before enc writes hs

    // CSR build (parallelized; per launch — d_ws is re-poisoned before every call)
    k_hist2   <<<NPB, 256, 0, stream>>>(ecol, chunkhist);
    k_scanA   <<<NBINS, 256, 0, stream>>>(chunkhist, bintot);
    k_scanC   <<<NBINS, 256, 0, stream>>>(chunkhist, bintot, binbase, chunkbase);
    k_binpass2<<<NPB, 256, 0, stream>>>(erow, ecol, chunkbase, pairs);
    k_csr2    <<<NBINS, 256, 0, stream>>>(pairs, binbase, indptr, dinv, rows_s);

    // encoder + conv step 1 fused
    k_encC<<<GGRID, 256, 0, stream>>>(X, W_enc0, b_enc0, W_enc1, b_enc1, W_conv, dinv, x, hs);

    // msg steps: lean gather kernel (fp8 rows); conv for next step separate (GEMM-shaped)
    k_agg_ln<<<N_NODES / 4, 256, 0, stream>>>((const uint2*)hs, (uint4*)x, dinv, indptr, rows_s,
                                              b_conv, ln_g, ln_b);
    k_convM <<<GGRID, 256, 0, stream>>>(x, W_conv, dinv, hs);
    k_agg_ln<<<N_NODES / 4, 256, 0, stream>>>((const uint2*)hs, (uint4*)x, dinv, indptr, rows_s,
                                              b_conv, ln_g, ln_b);
    k_convM <<<GGRID, 256, 0, stream>>>(x, W_conv, dinv, hs);
    k_agg_ln<<<N_NODES / 4, 256, 0, stream>>>((const uint2*)hs, (uint4*)x, dinv, indptr, rows_s,
                                              b_conv, ln_g, ln_b);

    k_decM<<<GGRID, 256, 0, stream>>>(x, W_dec0, b_dec0, W_dec1, b_dec1, out);
}

// Round 8
// 467.156 us; speedup vs baseline: 1.0677x; 1.0677x over previous
//
#include <hip/hip_runtime.h>

#define N_NODES 100000
#define NEDGE   3200000
#define DIN     16
#define DIM     128
#define DOUT    16
#define LN_EPS  1e-5f
#define NBINS   391          // 256-target bins: bin = c >> 8
#define CHUNK   4096         // edges per chunk block (smaller -> more parallel CSR build)
#define NPB     782          // ceil(NEDGE / CHUNK)
#define XS_STRIDE 136        // LDS bf16 row stride: 272B, 16B-aligned, 2-way-bank free
#define GGRID   1024         // GEMM grid
#define FP8_SCALE  64.0f     // pack scale: keeps hs out of e4m3 denormal zone
#define FP8_ISCALE 0.015625f

typedef __attribute__((ext_vector_type(8))) __bf16 bfrag_t;
typedef __attribute__((ext_vector_type(4))) float facc_t;
typedef __attribute__((ext_vector_type(2))) float fx2;

static __device__ __forceinline__ facc_t mfma16(bfrag_t a, bfrag_t b, facc_t c) {
    return __builtin_amdgcn_mfma_f32_16x16x32_bf16(a, b, c, 0, 0, 0);
}

// ---- bf16 helpers (RNE pack, cheap unpack) ----
static __device__ __forceinline__ unsigned f2bf(float f) {
    unsigned u = __float_as_uint(f);
    return (u + 0x7fffu + ((u >> 16) & 1u)) >> 16;
}
static __device__ __forceinline__ float bf_lo(unsigned u) { return __uint_as_float(u << 16); }
static __device__ __forceinline__ float bf_hi(unsigned u) { return __uint_as_float(u & 0xFFFF0000u); }

// ---- fp8 e4m3 (OCP on gfx950) HW converts ----
static __device__ __forceinline__ unsigned char f2fp8(float v) {
    return (unsigned char)__builtin_amdgcn_cvt_pk_fp8_f32(v, v, 0u, false);
}

// ---------------- CSR build: deterministic two-table partition ----------------
// pass 1: per-chunk histogram -> chunkhist[c][b]

__global__ __launch_bounds__(256) void k_hist2(const int* __restrict__ col,
                                               int* __restrict__ chunkhist) {
    __shared__ int lh[NBINS];
    int tid = threadIdx.x;
    for (int b = tid; b < NBINS; b += 256) lh[b] = 0;
    __syncthreads();
    int e0 = blockIdx.x * CHUNK;
    int e1 = e0 + CHUNK; if (e1 > NEDGE) e1 = NEDGE;
    for (int e = e0 + tid; e < e1; e += 256)
        atomicAdd(&lh[col[e] >> 8], 1);
    __syncthreads();
    int* out = chunkhist + (size_t)blockIdx.x * NBINS;
    for (int b = tid; b < NBINS; b += 256) out[b] = lh[b];
}

// pass 2a: bin totals (one block per bin, parallel over chunks)
__global__ __launch_bounds__(256) void k_scanA(const int* __restrict__ chunkhist,
                                               int* __restrict__ bintot) {
    __shared__ int sh[256];
    int b = blockIdx.x, t = threadIdx.x;
    int s = 0;
    for (int c = t; c < NPB; c += 256) s += chunkhist[(size_t)c * NBINS + b];
    sh[t] = s;
    __syncthreads();
    for (int off = 128; off > 0; off >>= 1) {
        if (t < off) sh[t] += sh[t + off];
        __syncthreads();
    }
    if (t == 0) bintot[b] = sh[0];
}

// pass 2b (1 tiny block): exclusive scan of 391 bin totals -> binbase
__global__ __launch_bounds__(512) void k_scanB(const int* __restrict__ bintot,
                                               int* __restrict__ binbase) {
    __shared__ int sh[512];
    int t = threadIdx.x;
    int v = (t < NBINS) ? bintot[t] : 0;
    sh[t] = v;
    __syncthreads();
    for (int off = 1; off < 512; off <<= 1) {
        int a = (t >= off) ? sh[t - off] : 0;
        __syncthreads();
        sh[t] += a;
        __syncthreads();
    }
    if (t < NBINS) binbase[t] = sh[t] - v;
    if (t == 0) binbase[NBINS] = NEDGE;
}

// pass 2c: per-bin prefix over chunks (one block per bin)
__global__ __launch_bounds__(256) void k_scanC(const int* __restrict__ chunkhist,
                                               const int* __restrict__ binbase,
                                               int* __restrict__ chunkbase) {
    __shared__ int sh[256];
    __shared__ int carry_s;
    int b = blockIdx.x, t = threadIdx.x;
    if (t == 0) carry_s = binbase[b];
    __syncthreads();
    const int ROUNDS = (NPB + 255) / 256;
    for (int r = 0; r < ROUNDS; r++) {
        int idx = r * 256 + t;
        int v = (idx < NPB) ? chunkhist[(size_t)idx * NBINS + b] : 0;
        sh[t] = v;
        __syncthreads();
        for (int off = 1; off < 256; off <<= 1) {
            int a = (t >= off) ? sh[t - off] : 0;
            __syncthreads();
            sh[t] += a;
            __syncthreads();
        }
        int incl = sh[t];
        int carry = carry_s;
        if (idx < NPB) chunkbase[(size_t)idx * NBINS + b] = carry + incl - v;
        __syncthreads();
        if (t == 255) carry_s = carry + incl;
        __syncthreads();
    }
}

// pass 3: single sweep over edges; scatter packed pairs at precomputed bases
__global__ __launch_bounds__(256) void k_binpass2(const int* __restrict__ row, const int* __restrict__ col,
                                                  const int* __restrict__ chunkbase,
                                                  unsigned* __restrict__ pairs) {
    __shared__ int lbase[NBINS], lofs[NBINS];
    int tid = threadIdx.x;
    const int* cb = chunkbase + (size_t)blockIdx.x * NBINS;
    for (int b = tid; b < NBINS; b += 256) { lbase[b] = cb[b]; lofs[b] = 0; }
    __syncthreads();
    int e0 = blockIdx.x * CHUNK;
    int e1 = e0 + CHUNK; if (e1 > NEDGE) e1 = NEDGE;
    for (int e = e0 + tid; e < e1; e += 256) {
        int c = col[e];
        int b = c >> 8;
        int pos = atomicAdd(&lofs[b], 1);
        pairs[lbase[b] + pos] = ((unsigned)(c & 255) << 17) | (unsigned)row[e];
    }
}

// pass 4: one block per bin -> per-node counts, indptr, dinv, scatter rows_s
__global__ __launch_bounds__(256) void k_csr2(const unsigned* __restrict__ pairs,
                                              const int* __restrict__ binbase,
                                              int* __restrict__ indptr, float* __restrict__ dinv,
                                              int* __restrict__ rows_s) {
    __shared__ int lcnt[256], lptr[256], lofs[256];
    __shared__ int wsum[4];
    int tid = threadIdx.x;
    int b = blockIdx.x;
    int n0 = b << 8;
    int base = binbase[b], end = binbase[b + 1];
    lcnt[tid] = 0; lofs[tid] = 0;
    __syncthreads();
    for (int s = base + tid; s < end; s += 256)
        atomicAdd(&lcnt[pairs[s] >> 17], 1);
    __syncthreads();
    int v = lcnt[tid];
    int lane = tid & 63, w = tid >> 6;
    int s = v;
    for (int off = 1; off < 64; off <<= 1) {
        int t = __shfl_up(s, off);
        if (lane >= off) s += t;
    }
    if (lane == 63) wsum[w] = s;
    __syncthreads();
    int add = 0;
    for (int k = 0; k < w; k++) add += wsum[k];
    int excl = add + s - v;
    lptr[tid] = excl;
    int node = n0 + tid;
    if (node < N_NODES) {
        indptr[node] = base + excl;
        dinv[node] = rsqrtf((float)(v + 1));   // +1 self loop
    }
    if (b == NBINS - 1 && tid == 0) indptr[N_NODES] = NEDGE;
    __syncthreads();
    for (int s2 = base + tid; s2 < end; s2 += 256) {
        unsigned p = pairs[s2];
        int cl = p >> 17;
        int r  = p & 0x1FFFF;
        int dst = base + lptr[cl] + atomicAdd(&lofs[cl], 1);
        rows_s[dst] = r;
    }
}

// ---------------- MFMA helpers ----------------
template<int NC, int NT>
static __device__ __forceinline__ void load_bfrags(const float* __restrict__ W, int colbase,
                                                   int lane, bfrag_t B[NT][4]) {
    int q = lane >> 4, nn = lane & 15;
    #pragma unroll
    for (int nt = 0; nt < NT; nt++) {
        int col = colbase + 16 * nt + nn;
        #pragma unroll
        for (int kc = 0; kc < 4; kc++) {
            int k0 = 32 * kc + 8 * q;
            bfrag_t f;
            #pragma unroll
            for (int j = 0; j < 8; j++)
                f[j] = (__bf16)W[(size_t)(k0 + j) * NC + col];
            B[nt][kc] = f;
        }
    }
}

// stage 32 bf16 rows (256B each) -> LDS tile (stride XS_STRIDE), straight copy
static __device__ __forceinline__ void stage_bf(const unsigned short* __restrict__ src_base,
                                                short* __restrict__ xs, int tid) {
    int r = tid >> 3, s = tid & 7;   // 8 threads/row, 32B each
    const uint4* src = (const uint4*)(src_base + (size_t)r * DIM + 16 * s);
    uint4 a = src[0], b = src[1];
    *(uint4*)&xs[r * XS_STRIDE + 16 * s] = a;
    *(uint4*)&xs[r * XS_STRIDE + 16 * s + 8] = b;
}

// MFMA conv block: ys (32 rows bf16 in LDS) @ W-frags -> hs rows nb..nb+31 (fp8),
// scaled by dinv*FP8_SCALE
static __device__ __forceinline__ void conv_tail(const short* __restrict__ ys, bfrag_t B[2][4],
                                                 const float* __restrict__ dinv, int nb,
                                                 int lane, int wv, unsigned char* __restrict__ hs_out) {
    int q = lane >> 4, nn = lane & 15;
    facc_t a2[2][2] = {};
    #pragma unroll
    for (int kc = 0; kc < 4; kc++) {
        bfrag_t a0 = *(const bfrag_t*)&ys[nn * XS_STRIDE + 32 * kc + 8 * q];
        bfrag_t a1 = *(const bfrag_t*)&ys[(16 + nn) * XS_STRIDE + 32 * kc + 8 * q];
        a2[0][0] = mfma16(a0, B[0][kc], a2[0][0]);
        a2[0][1] = mfma16(a0, B[1][kc], a2[0][1]);
        a2[1][0] = mfma16(a1, B[0][kc], a2[1][0]);
        a2[1][1] = mfma16(a1, B[1][kc], a2[1][1]);
    }
    #pragma unroll
    for (int mt = 0; mt < 2; mt++)
        #pragma unroll
        for (int r = 0; r < 4; r++) {
            int node = nb + 16 * mt + 4 * q + r;
            float d64 = dinv[node] * FP8_SCALE;
            #pragma unroll
            for (int nt = 0; nt < 2; nt++)
                hs_out[(size_t)node * DIM + 32 * wv + 16 * nt + nn] =
                    f2fp8(a2[mt][nt][r] * d64);
        }
}

// ---------------- encoder (fused): x_bf16 = relu(X@W0+b0)@W1+b1 ; hs = fp8((x@Wc)*dinv*64) ----------------

__global__ __launch_bounds__(256) void k_encC(const float* __restrict__ X,
                                              const float* __restrict__ W0, const float* __restrict__ b0,
                                              const float* __restrict__ W1, const float* __restrict__ b1,
                                              const float* __restrict__ Wc, const float* __restrict__ dinv,
                                              unsigned short* __restrict__ xo, unsigned char* __restrict__ hs_out) {
    __shared__ short xs[32 * XS_STRIDE];
    __shared__ float W0s[DIN * DIM];   // 8 KB
    __shared__ float b0s[DIM];
    int tid = threadIdx.x, lane = tid & 63, wv = tid >> 6;
    for (int i = tid; i < DIN * DIM / 4; i += 256) ((float4*)W0s)[i] = ((const float4*)W0)[i];
    if (tid < DIM) b0s[tid] = b0[tid];
    bfrag_t B[2][4];
    load_bfrags<DIM, 2>(W1, 32 * wv, lane, B);
    bfrag_t Bc[2][4];
    load_bfrags<DIM, 2>(Wc, 32 * wv, lane, Bc);
    int q = lane >> 4, nn = lane & 15;
    float bias[2] = { b1[32 * wv + nn], b1[32 * wv + 16 + nn] };
    const int ngroups = N_NODES / 32;
    for (int g = blockIdx.x; g < ngroups; g += gridDim.x) {
        int n0 = g * 32;
        __syncthreads();
        {   // stage: t = relu(X@W0+b0), node r, cols 16s..16s+15 -> bf16 LDS
            int r = tid >> 3, s = tid & 7;
            float xr[DIN];
            const float4* xsrc = (const float4*)(X + (size_t)(n0 + r) * DIN);
            #pragma unroll
            for (int i = 0; i < 4; i++) {
                float4 v = xsrc[i];
                xr[4*i] = v.x; xr[4*i+1] = v.y; xr[4*i+2] = v.z; xr[4*i+3] = v.w;
            }
            unsigned pk[8];
            #pragma unroll
            for (int cc = 0; cc < 16; cc += 2) {
                int c0 = 16 * s + cc;
                float a0 = b0s[c0], a1 = b0s[c0 + 1];
                #pragma unroll
                for (int k = 0; k < DIN; k++) {
                    float2 w = *(const float2*)&W0s[k * DIM + c0];
                    a0 += xr[k] * w.x; a1 += xr[k] * w.y;
                }
                pk[cc >> 1] = f2bf(fmaxf(a0, 0.f)) | (f2bf(fmaxf(a1, 0.f)) << 16);
            }
            *(uint4*)&xs[r * XS_STRIDE + 16 * s] = *(uint4*)&pk[0];
            *(uint4*)&xs[r * XS_STRIDE + 16 * s + 8] = *(uint4*)&pk[4];
        }
        __syncthreads();
        facc_t acc[2][2];
        #pragma unroll
        for (int mt = 0; mt < 2; mt++)
            #pragma unroll
            for (int nt = 0; nt < 2; nt++)
                acc[mt][nt] = (facc_t){bias[nt], bias[nt], bias[nt], bias[nt]};
        #pragma unroll
        for (int kc = 0; kc < 4; kc++) {
            bfrag_t a0 = *(const bfrag_t*)&xs[nn * XS_STRIDE + 32 * kc + 8 * q];
            bfrag_t a1 = *(const bfrag_t*)&xs[(16 + nn) * XS_STRIDE + 32 * kc + 8 * q];
            acc[0][0] = mfma16(a0, B[0][kc], acc[0][0]);
            acc[0][1] = mfma16(a0, B[1][kc], acc[0][1]);
            acc[1][0] = mfma16(a1, B[0][kc], acc[1][0]);
            acc[1][1] = mfma16(a1, B[1][kc], acc[1][1]);
        }
        // write x (bf16) and re-stage x tile as bf16 for the fused conv
        __syncthreads();   // all A-reads done; xs can be overwritten
        #pragma unroll
        for (int mt = 0; mt < 2; mt++)
            #pragma unroll
            for (int r = 0; r < 4; r++) {
                int node = n0 + 16 * mt + 4 * q + r;
                int nl = 16 * mt + 4 * q + r;
                #pragma unroll
                for (int nt = 0; nt < 2; nt++) {
                    int col = 32 * wv + 16 * nt + nn;
                    unsigned short bv = (unsigned short)f2bf(acc[mt][nt][r]);
                    xo[(size_t)node * DIM + col] = bv;
                    xs[nl * XS_STRIDE + col] = (short)bv;
                }
            }
        __syncthreads();
        conv_tail(xs, Bc, dinv, n0, lane, wv, hs_out);
    }
}

// ---------------- conv: hs_fp8 = fp8((x_bf16 @ W_conv) * dinv * 64) ----------------

__global__ __launch_bounds__(256) void k_convM(const unsigned short* __restrict__ xi,
                                               const float* __restrict__ W,
                                               const float* __restrict__ dinv,
                                               unsigned char* __restrict__ hs) {
    __shared__ short xs[32 * XS_STRIDE];
    int tid = threadIdx.x, lane = tid & 63, wv = tid >> 6;
    bfrag_t B[2][4];
    load_bfrags<DIM, 2>(W, 32 * wv, lane, B);
    const int ngroups = N_NODES / 32;
    for (int g = blockIdx.x; g < ngroups; g += gridDim.x) {
        int n0 = g * 32;
        __syncthreads();
        stage_bf(xi + (size_t)n0 * DIM, xs, tid);
        __syncthreads();
        conv_tail(xs, B, dinv, n0, lane, wv, hs);
    }
}

// ---------------- fused gather + residual + bias + LayerNorm (hs fp8, x bf16) ----------------
// packed-f32 accumulation (v_pk_add_f32); inline shuffles (no runtime-indexed array ->
// no scratch risk, ds_bpermute is off the VALU pipe); 32-bit byte-offset addressing.

static __device__ __forceinline__ void accp(fx2* __restrict__ acc, uint2 u) {
    acc[0] += __builtin_amdgcn_cvt_pk_f32_fp8(u.x, false);
    acc[1] += __builtin_amdgcn_cvt_pk_f32_fp8(u.x, true);
    acc[2] += __builtin_amdgcn_cvt_pk_f32_fp8(u.y, false);
    acc[3] += __builtin_amdgcn_cvt_pk_f32_fp8(u.y, true);
}

__global__ __launch_bounds__(256) void k_agg_ln(const uint2* __restrict__ hs2, uint4* __restrict__ x4,
                                                const float* __restrict__ dinv,
                                                const int* __restrict__ indptr,
                                                const int* __restrict__ rows_s,
                                                const float* __restrict__ bconv,
                                                const float* __restrict__ g_, const float* __restrict__ b_) {
    int v = (blockIdx.x * blockDim.x + threadIdx.x) >> 6;
    int lane = threadIdx.x & 63;
    if (v >= N_NODES) return;
    int sub = lane >> 4, part = lane & 15;
    const char* hsb = (const char*)hs2;
    unsigned pb = (unsigned)part << 3;        // byte offset of this lane's 8B slice
    fx2 acc[4];
    #pragma unroll
    for (int j = 0; j < 4; j++) acc[j] = (fx2){0.f, 0.f};
    {   // self loop: count once (sub 0 only)
        uint2 u = *(const uint2*)(hsb + (((unsigned)v << 7) | pb));
        if (sub == 0) accp(acc, u);
    }
    int beg = indptr[v], end = indptr[v + 1];
    for (int base = beg; base < end; base += 64) {
        int m = end - base; if (m > 64) m = 64;
        int r0 = rows_s[base + (lane < m ? lane : m - 1)];
        int k = 0;
        for (; k + 16 <= m; k += 16) {        // 4 independent loads in flight, 16 edges
            int ia = __shfl(r0, k + sub);
            int ib = __shfl(r0, k + 4 + sub);
            int ic = __shfl(r0, k + 8 + sub);
            int id = __shfl(r0, k + 12 + sub);
            uint2 ua = *(const uint2*)(hsb + (((unsigned)ia << 7) | pb));
            uint2 ub = *(const uint2*)(hsb + (((unsigned)ib << 7) | pb));
            uint2 uc = *(const uint2*)(hsb + (((unsigned)ic << 7) | pb));
            uint2 ud = *(const uint2*)(hsb + (((unsigned)id << 7) | pb));
            accp(acc, ua); accp(acc, ub); accp(acc, uc); accp(acc, ud);
        }
        for (; k + 4 <= m; k += 4) {          // 4-edge steps
            int i = __shfl(r0, k + sub);
            uint2 u = *(const uint2*)(hsb + (((unsigned)i << 7) | pb));
            accp(acc, u);
        }
        if (k < m) {                          // predicated partial group
            int kk = k + sub;
            bool valid = kk < m;
            int i = __shfl(r0, valid ? kk : m - 1);
            uint2 u = *(const uint2*)(hsb + (((unsigned)i << 7) | pb));
            if (valid) accp(acc, u);
        }
    }
    float a8[8];
    #pragma unroll
    for (int j = 0; j < 4; j++) { a8[2 * j] = acc[j][0]; a8[2 * j + 1] = acc[j][1]; }
    #pragma unroll
    for (int j = 0; j < 8; j++) {             // sum the 4 sub-copies
        a8[j] += __shfl_xor(a8[j], 16);
        a8[j] += __shfl_xor(a8[j], 32);
    }
    float dvs = dinv[v] * FP8_ISCALE;         // undo FP8_SCALE here
    float y[8];
    {
        uint4 xu = x4[(size_t)v * 16 + part];
        const float4* bc = (const float4*)(bconv + 8 * part);
        float4 b0 = bc[0], b1 = bc[1];
        y[0] = bf_lo(xu.x) + dvs * a8[0] + b0.x; y[1] = bf_hi(xu.x) + dvs * a8[1] + b0.y;
        y[2] = bf_lo(xu.y) + dvs * a8[2] + b0.z; y[3] = bf_hi(xu.y) + dvs * a8[3] + b0.w;
        y[4] = bf_lo(xu.z) + dvs * a8[4] + b1.x; y[5] = bf_hi(xu.z) + dvs * a8[5] + b1.y;
        y[6] = bf_lo(xu.w) + dvs * a8[6] + b1.z; y[7] = bf_hi(xu.w) + dvs * a8[7] + b1.w;
    }
    float s = 0.f, s2 = 0.f;
    #pragma unroll
    for (int j = 0; j < 8; j++) { s += y[j]; s2 += y[j] * y[j]; }
    #pragma unroll
    for (int off = 1; off < 16; off <<= 1) {  // reduce within 16-lane group (covers all parts)
        s += __shfl_xor(s, off);
        s2 += __shfl_xor(s2, off);
    }
    float mu = s * (1.f / 128.f);
    float rstd = rsqrtf(s2 * (1.f / 128.f) - mu * mu + LN_EPS);
    if (sub == 0) {
        const float4* gp = (const float4*)(g_ + 8 * part);
        const float4* bp = (const float4*)(b_ + 8 * part);
        float4 g0 = gp[0], g1 = gp[1];
        float4 bb0 = bp[0], bb1 = bp[1];
        float o[8];
        o[0] = (y[0] - mu) * rstd * g0.x + bb0.x;
        o[1] = (y[1] - mu) * rstd * g0.y + bb0.y;
        o[2] = (y[2] - mu) * rstd * g0.z + bb0.z;
        o[3] = (y[3] - mu) * rstd * g0.w + bb0.w;
        o[4] = (y[4] - mu) * rstd * g1.x + bb1.x;
        o[5] = (y[5] - mu) * rstd * g1.y + bb1.y;
        o[6] = (y[6] - mu) * rstd * g1.z + bb1.z;
        o[7] = (y[7] - mu) * rstd * g1.w + bb1.w;
        uint4 ow;
        ow.x = f2bf(o[0]) | (f2bf(o[1]) << 16);
        ow.y = f2bf(o[2]) | (f2bf(o[3]) << 16);
        ow.z = f2bf(o[4]) | (f2bf(o[5]) << 16);
        ow.w = f2bf(o[6]) | (f2bf(o[7]) << 16);
        x4[(size_t)v * 16 + part] = ow;
    }
}

// ---------------- decoder (fused): out = relu(x@W0+b0)@W1 + b1 ----------------

__global__ __launch_bounds__(256) void k_decM(const unsigned short* __restrict__ xi,
                                              const float* __restrict__ W0, const float* __restrict__ b0f,
                                              const float* __restrict__ W1, const float* __restrict__ b1f,
                                              float* __restrict__ out) {
    __shared__ short xs[32 * XS_STRIDE];
    int tid = threadIdx.x, lane = tid & 63, wv = tid >> 6;
    bfrag_t B0[2][4];
    load_bfrags<DIM, 2>(W0, 32 * wv, lane, B0);
    int q = lane >> 4, nn = lane & 15;
    bfrag_t B1[4];
    #pragma unroll
    for (int kc = 0; kc < 4; kc++) {
        int k0 = 32 * kc + 8 * q;
        bfrag_t f;
        #pragma unroll
        for (int j = 0; j < 8; j++)
            f[j] = (__bf16)W1[(size_t)(k0 + j) * DOUT + nn];
        B1[kc] = f;
    }
    float bias0[2] = { b0f[32 * wv + nn], b0f[32 * wv + 16 + nn] };
    float bias1 = b1f[nn];
    const int ngroups = N_NODES / 32;
    for (int g = blockIdx.x; g < ngroups; g += gridDim.x) {
        int n0 = g * 32;
        __syncthreads();
        stage_bf(xi + (size_t)n0 * DIM, xs, tid);
        __syncthreads();
        facc_t acc[2][2];
        #pragma unroll
        for (int mt = 0; mt < 2; mt++)
            #pragma unroll
            for (int nt = 0; nt < 2; nt++)
                acc[mt][nt] = (facc_t){bias0[nt], bias0[nt], bias0[nt], bias0[nt]};
        #pragma unroll
        for (int kc = 0; kc < 4; kc++) {
            bfrag_t a0 = *(const bfrag_t*)&xs[nn * XS_STRIDE + 32 * kc + 8 * q];
            bfrag_t a1 = *(const bfrag_t*)&xs[(16 + nn) * XS_STRIDE + 32 * kc + 8 * q];
            acc[0][0] = mfma16(a0, B0[0][kc], acc[0][0]);
            acc[0][1] = mfma16(a0, B0[1][kc], acc[0][1]);
            acc[1][0] = mfma16(a1, B0[0][kc], acc[1][0]);
            acc[1][1] = mfma16(a1, B0[1][kc], acc[1][1]);
        }
        __syncthreads();   // all A-reads of x-tile done; xs can be overwritten
        #pragma unroll
        for (int mt = 0; mt < 2; mt++)
            #pragma unroll
            for (int nt = 0; nt < 2; nt++)
                #pragma unroll
                for (int r = 0; r < 4; r++) {
                    int nl = 16 * mt + 4 * q + r;
                    int col = 32 * wv + 16 * nt + nn;
                    xs[nl * XS_STRIDE + col] = (short)f2bf(fmaxf(acc[mt][nt][r], 0.f));
                }
        __syncthreads();
        if (wv < 2) {   // waves 0,1: t2[32x128] @ W1[128x16]
            facc_t acc2 = (facc_t){bias1, bias1, bias1, bias1};
            #pragma unroll
            for (int kc = 0; kc < 4; kc++) {
                bfrag_t a = *(const bfrag_t*)&xs[(16 * wv + nn) * XS_STRIDE + 32 * kc + 8 * q];
                acc2 = mfma16(a, B1[kc], acc2);
            }
            #pragma unroll
            for (int r = 0; r < 4; r++) {
                int node = n0 + 16 * wv + 4 * q + r;
                out[(size_t)node * DOUT + nn] = acc2[r];
            }
        }
    }
}

// ---------------- launch ----------------

extern "C" void kernel_launch(void* const* d_in, const int* in_sizes, int n_in,
                              void* d_out, int out_size, void* d_ws, size_t ws_size,
                              hipStream_t stream) {
    const float* X      = (const float*)d_in[0];
    const float* W_enc0 = (const float*)d_in[1];
    const float* b_enc0 = (const float*)d_in[2];
    const float* W_enc1 = (const float*)d_in[3];
    const float* b_enc1 = (const float*)d_in[4];
    const float* W_conv = (const float*)d_in[5];
    const float* b_conv = (const float*)d_in[6];
    const float* ln_g   = (const float*)d_in[7];
    const float* ln_b   = (const float*)d_in[8];
    const float* W_dec0 = (const float*)d_in[9];
    const float* b_dec0 = (const float*)d_in[10];
    const float* W_dec1 = (const float*)d_in[11];
    const float* b_dec1 = (const float*)d_in[12];
    const int*   erow   = (const int*)d_in[13];         // edge_index[0] = sources
    const int*   ecol   = erow + NEDGE;                 // edge_index[1] = targets
    float* out = (float*)d_out;

    unsigned short* x         = (unsigned short*)d_ws;                       // N*128 bf16 (25.6 MB)
    unsigned char*  hs        = (unsigned char*)(x + (size_t)N_NODES * DIM); // N*128 fp8 (12.8 MB)
    float*          dinv      = (float*)(hs + (size_t)N_NODES * DIM);        // N f32
    int*            indptr    = (int*)(dinv + N_NODES);                      // N+1 int
    int*            binbase   = indptr + N_NODES + 8;                        // NBINS+1
    int*            bintot    = binbase + NBINS + 9;                         // NBINS
    int*            chunkhist = bintot + NBINS + 8;                          // NPB*NBINS
    int*            chunkbase = chunkhist + NPB * NBINS + 8;                 // NPB*NBINS
    int*            rows_s    = chunkbase + NPB * NBINS + 8;                 // E int
    unsigned*       pairs     = (unsigned*)hs;   // overlay: E*4B == N*128B exactly; consumed before enc writes hs

    // CSR build (parallelized; per launch — d_ws is re-poisoned before every call)
    k_hist2   <<<NPB, 256, 0, stream>>>(ecol, chunkhist);
    k_scanA   <<<NBINS, 256, 0, stream>>>(chunkhist, bintot);
    k_scanB   <<<1, 512, 0, stream>>>(bintot, binbase);
    k_scanC   <<<NBINS, 256, 0, stream>>>(chunkhist, binbase, chunkbase);
    k_binpass2<<<NPB, 256, 0, stream>>>(erow, ecol, chunkbase, pairs);
    k_csr2    <<<NBINS, 256, 0, stream>>>(pairs, binbase, indptr, dinv, rows_s);

    // encoder + conv step 1 fused
    k_encC<<<GGRID, 256, 0, stream>>>(X, W_enc0, b_enc0, W_enc1, b_enc1, W_conv, dinv, x, hs);

    // msg steps: lean gather kernel (fp8 rows); conv for next step separate (GEMM-shaped)
    k_agg_ln<<<N_NODES / 4, 256, 0, stream>>>((const uint2*)hs, (uint4*)x, dinv, indptr, rows_s,
                                              b_conv, ln_g, ln_b);
    k_convM <<<GGRID, 256, 0, stream>>>(x, W_conv, dinv, hs);
    k_agg_ln<<<N_NODES / 4, 256, 0, stream>>>((const uint2*)hs, (uint4*)x, dinv, indptr, rows_s,
                                              b_conv, ln_g, ln_b);
    k_convM <<<GGRID, 256, 0, stream>>>(x, W_conv, dinv, hs);
    k_agg_ln<<<N_NODES / 4, 256, 0, stream>>>((const uint2*)hs, (uint4*)x, dinv, indptr, rows_s,
                                              b_conv, ln_g, ln_b);

    k_decM<<<GGRID, 256, 0, stream>>>(x, W_dec0, b_dec0, W_dec1, b_dec1, out);
}